// Round 6
// baseline (1114.027 us; speedup 1.0000x reference)
//
#include <hip/hip_runtime.h>
#include <hip/hip_bf16.h>
#include <cstdint>

// NeighborhoodAttentionS2: B=2, C=256, H=128, W=256
// k_prep: weights->bf16 (q-scale folded), query -> qT[b][hw][c] bf16 (staged in d_out), rowptr
// k_qkv : barrier-free MFMA GEMM, A/B fragments direct from global; q/k -> [point][c], v -> vT[b][h][c][w]
// k_attn: per (b,ho,quarter) block, 4 independent waves (16-wo strips), QK^T/PV fragments
//         direct from L2, masked online softmax w/ defer-max, direct coalesced f32x4 stores.
// ws: qB[32MB] | kB[32MB] | vT[32MB] | Wbf[384KB] | rp[129]

#define NLAT 128
#define NLON 256
#define NCH  256
#define HWSZ (NLAT * NLON)
#define SEGN 11

typedef __attribute__((ext_vector_type(4))) float f32x4;
typedef __attribute__((ext_vector_type(8))) short s16x8;

__device__ __forceinline__ float bf2f(unsigned int hi_bits) {
    return __uint_as_float(hi_bits);
}
__device__ __forceinline__ unsigned short f2bf(float f) {
    unsigned int u = __float_as_uint(f);
    return (unsigned short)((u + 0x7fffu + ((u >> 16) & 1u)) >> 16);
}

// ---------------- prep: qT transpose + weight convert + rowptr ----------------
// grid 4100: [0,4096) query transpose tiles; 4096..4098 weights; 4099 rowptr
__global__ __launch_bounds__(256) void k_prep(
    const float* __restrict__ query,
    const float* __restrict__ qw, const float* __restrict__ kw, const float* __restrict__ vw,
    const int* __restrict__ rows, int nnz,
    unsigned short* __restrict__ qT, unsigned short* __restrict__ Wbf, int* __restrict__ rp)
{
    const int bid = blockIdx.x;
    const int tid = threadIdx.x;
    if (bid < 4096) {
        __shared__ unsigned short T[64][66];
        const int b   = bid >> 11;
        const int ct  = (bid >> 9) & 3;
        const int hw0 = (bid & 511) * 64;
        const float* src = query + (size_t)b * NCH * HWSZ + (size_t)(ct * 64) * HWSZ + hw0;
        const int hw_l = tid & 63;
        const int csub = tid >> 6;
        #pragma unroll
        for (int r = 0; r < 16; ++r) {
            const int c_l = r * 4 + csub;
            T[c_l][hw_l] = f2bf(src[(size_t)c_l * HWSZ + hw_l]);
        }
        __syncthreads();
        const int c_l2 = tid & 63;
        const int hsub = tid >> 6;
        #pragma unroll
        for (int r = 0; r < 16; ++r) {
            const int hw_l2 = r * 4 + hsub;
            qT[((size_t)(b * HWSZ + hw0 + hw_l2) << 8) + ct * 64 + c_l2] = T[c_l2][hw_l2];
        }
    } else if (bid < 4099) {
        const int y = bid - 4096;
        const float* src = (y == 0) ? qw : (y == 1) ? kw : vw;
        const float scale = (y == 0) ? 0.0625f : 1.0f;
        unsigned short* dst = Wbf + y * 65536;
        for (int i = tid; i < 65536; i += 256) dst[i] = f2bf(src[i] * scale);
    } else {
        const int ho = tid;
        if (ho > NLAT) return;
        int lo = 0, hi = nnz;
        while (lo < hi) {
            int mid = (lo + hi) >> 1;
            if (rows[mid] < ho) lo = mid + 1; else hi = mid;
        }
        rp[ho] = lo;
    }
}

// ---------------- barrier-free QKV GEMM ----------------
// grid (512 nt, 2 mt, 3 y), block 256 = 4 waves (2 wm x 2 wn). Wave: 64m x 64n, K=256.
__global__ __launch_bounds__(256, 2) void k_qkv(
    const unsigned short* __restrict__ Wbf,
    const unsigned short* __restrict__ qT,
    const float* __restrict__ qb, const float* __restrict__ kb, const float* __restrict__ vb,
    unsigned short* __restrict__ qB, unsigned short* __restrict__ kB, unsigned short* __restrict__ vT)
{
    __shared__ unsigned short Tv[4][16][18];
    const int nt = blockIdx.x, mt = blockIdx.y, y = blockIdx.z;
    const int tid  = threadIdx.x;
    const int lane = tid & 63;
    const int wv   = tid >> 6;
    const int l15  = lane & 15;
    const int g    = lane >> 4;
    const int wm = wv >> 1, wn = wv & 1;

    const int m0    = mt * 128 + wm * 64;
    const int nbase = nt * 128 + wn * 64;      // global point incl. batch
    const unsigned short* Wy   = Wbf + y * 65536;
    const unsigned short* qrow = qT + ((size_t)nbase << 8);
    const float* bias = (y == 0) ? qb : (y == 1) ? kb : vb;

    f32x4 acc[4][4] = {};
    #pragma unroll
    for (int kk = 0; kk < 8; ++kk) {
        s16x8 af[4], bfr[4];
        #pragma unroll
        for (int i = 0; i < 4; ++i)
            af[i] = *(const s16x8*)(Wy + (size_t)((m0 + i * 16 + l15) << 8) + kk * 32 + g * 8);
        #pragma unroll
        for (int j = 0; j < 4; ++j)
            bfr[j] = *(const s16x8*)(qrow + (size_t)((j * 16 + l15) << 8) + kk * 32 + g * 8);
        #pragma unroll
        for (int i = 0; i < 4; ++i)
            #pragma unroll
            for (int j = 0; j < 4; ++j)
                acc[i][j] = __builtin_amdgcn_mfma_f32_16x16x32_bf16(af[i], bfr[j], acc[i][j], 0, 0, 0);
    }

    if (y < 2) {
        unsigned short* outp = (y == 0) ? qB : kB;
        #pragma unroll
        for (int i = 0; i < 4; ++i) {
            const int c0 = m0 + i * 16 + 4 * g;
            const float4 bv = *(const float4*)(bias + c0);
            #pragma unroll
            for (int j = 0; j < 4; ++j) {
                const int point = nbase + j * 16 + l15;
                ushort4 st;
                st.x = f2bf(acc[i][j][0] + bv.x);
                st.y = f2bf(acc[i][j][1] + bv.y);
                st.z = f2bf(acc[i][j][2] + bv.z);
                st.w = f2bf(acc[i][j][3] + bv.w);
                *(ushort4*)(outp + ((size_t)point << 8) + c0) = st;
            }
        }
    } else {
        const int b  = nbase >> 15;
        const int pt = nbase & (HWSZ - 1);
        const int h  = pt >> 8;
        const int w0 = pt & 255;
        #pragma unroll
        for (int i = 0; i < 4; ++i) {
            const int c0 = m0 + i * 16 + 4 * g;
            const float4 bv = *(const float4*)(bias + c0);
            #pragma unroll
            for (int j = 0; j < 4; ++j) {
                Tv[wv][4 * g + 0][l15] = f2bf(acc[i][j][0] + bv.x);
                Tv[wv][4 * g + 1][l15] = f2bf(acc[i][j][1] + bv.y);
                Tv[wv][4 * g + 2][l15] = f2bf(acc[i][j][2] + bv.z);
                Tv[wv][4 * g + 3][l15] = f2bf(acc[i][j][3] + bv.w);
                __builtin_amdgcn_s_waitcnt(0);   // lgkmcnt(0): wave-private transpose
                const ushort4 tv = *(const ushort4*)&Tv[wv][l15][g * 4];
                *(ushort4*)(vT + (((size_t)((b * 128 + h) * 256 + m0 + i * 16 + l15)) << 8)
                               + w0 + j * 16 + g * 4) = tv;
                __builtin_amdgcn_s_waitcnt(0);
            }
        }
    }
}

// ---------------- direct-from-L2 MFMA neighborhood attention ----------------
// grid 1024, block 256 = 4 independent waves (16-wo strips). No barriers after mask build.
// Swizzle: XCD k gets north band ho[8k,8k+8) + mirrored south band (work-symmetric).
__global__ __launch_bounds__(256, 4) void k_attn(
    const unsigned short* __restrict__ qB,
    const unsigned short* __restrict__ kB,
    const unsigned short* __restrict__ vT,
    const int* __restrict__ psi_col,
    const float* __restrict__ qwt,
    const int* __restrict__ rp,
    float* __restrict__ out)
{
    __shared__ unsigned int segmask[SEGN][8];
    __shared__ int seg_dlo[SEGN], seg_ext[SEGN];
    __shared__ unsigned short als[4][16][40];

    const int bid = blockIdx.x;
    const int xcd = bid & 7;
    const int t   = bid >> 3;
    const int b   = t >> 6;
    const int q4  = t & 3;
    const int i16 = (t >> 2) & 15;
    const int ho  = (i16 < 8) ? (xcd * 8 + i16) : (127 - xcd * 8 - (i16 - 8));
    const int wo0 = q4 * 64;

    const int tid  = threadIdx.x;
    const int lane = tid & 63;
    const int wv   = tid >> 6;
    const int l15  = lane & 15;
    const int g    = lane >> 4;

    // ---- per-(ho,hi) exact masks from CSR ----
    for (int i = tid; i < SEGN * 8; i += 256) ((unsigned*)segmask)[i] = 0u;
    __syncthreads();
    const int r0 = rp[ho], r1 = rp[ho + 1];
    for (int n = r0 + tid; n < r1; n += 256) {
        const int col = psi_col[n];
        const int s = (col >> 8) - ho + 5;
        if ((unsigned)s < SEGN) atomicOr(&segmask[s][(col & 255) >> 5], 1u << (col & 31));
    }
    __syncthreads();
    if (tid < SEGN) {
        const int hi = ho - 5 + tid;
        int dlo = 0, ext = 0;
        if (hi >= 0 && hi < 128) {
            unsigned mw[8]; int pc = 0;
            for (int w = 0; w < 8; ++w) { mw[w] = segmask[tid][w]; pc += __popc(mw[w]); }
            if (pc >= 256) { dlo = 0; ext = 256; }
            else if (pc > 0) {
                int tr = 0; bool run = true;
                for (int w = 0; w < 8; ++w) {
                    if (!run) break;
                    if (mw[w] == 0xffffffffu) tr += 32;
                    else { tr += __ffs(~mw[w]) - 1; run = false; }
                }
                int z = 0; run = true;
                for (int w = 7; w >= 0; --w) {
                    if (!run) break;
                    if (mw[w] == 0xffffffffu) z += 32;
                    else { z += __clz(~mw[w]); run = false; }
                }
                if (pc == tr + z && tr + z <= 256) { dlo = -z; ext = pc; }
                else { dlo = 0; ext = 256; }
            }
        }
        seg_dlo[tid] = dlo; seg_ext[tid] = ext;
    }
    __syncthreads();

    // ---- wave-private strip ----
    const int ws0 = wo0 + wv * 16;
    const size_t qpt = ((size_t)(b * HWSZ + ho * 256 + ws0 + l15)) << 8;
    s16x8 af[8];
    #pragma unroll
    for (int ck = 0; ck < 8; ++ck) af[ck] = *(const s16x8*)(qB + qpt + ck * 32 + g * 8);

    f32x4 O[16] = {};
    float M[4] = {-1e38f, -1e38f, -1e38f, -1e38f};
    float L[4] = {0.f, 0.f, 0.f, 0.f};

    const size_t kbb = ((size_t)(b * HWSZ)) << 8;
    const unsigned short* vbb = vT + (((size_t)(b * 128)) << 8) * 256;

    for (int s = 0; s < SEGN; ++s) {
        const int ext = seg_ext[s];
        if (ext == 0) continue;
        const int dlo = seg_dlo[s];
        const int hi  = ho - 5 + s;
        const float qw = qwt[hi];
        const unsigned mk0 = __builtin_amdgcn_readfirstlane(segmask[s][0]);
        const unsigned mk1 = __builtin_amdgcn_readfirstlane(segmask[s][1]);
        const unsigned mk2 = __builtin_amdgcn_readfirstlane(segmask[s][2]);
        const unsigned mk3 = __builtin_amdgcn_readfirstlane(segmask[s][3]);
        const unsigned mk4 = __builtin_amdgcn_readfirstlane(segmask[s][4]);
        const unsigned mk5 = __builtin_amdgcn_readfirstlane(segmask[s][5]);
        const unsigned mk6 = __builtin_amdgcn_readfirstlane(segmask[s][6]);
        const unsigned mk7 = __builtin_amdgcn_readfirstlane(segmask[s][7]);

        const int dlo8 = dlo & ~7;
        const int pad  = dlo - dlo8;
        int jtot = 15 + pad + ext; if (jtot > 256) jtot = 256;
        const int wbase = (ws0 + dlo8) & 255;
        const unsigned short* kptr = kB + kbb + (((size_t)(hi * 256)) << 8);
        const unsigned short* vptr = vbb + (((size_t)(hi * 256)) << 8);

        for (int j0 = 0; j0 < jtot; j0 += 32) {
            f32x4 S[2];
            __builtin_amdgcn_s_setprio(1);
            #pragma unroll
            for (int jt = 0; jt < 2; ++jt) {
                const int wil = (wbase + j0 + jt * 16 + l15) & 255;
                const unsigned short* kp = kptr + (((size_t)wil) << 8) + g * 8;
                f32x4 a = {};
                #pragma unroll
                for (int ck = 0; ck < 8; ++ck) {
                    const s16x8 bf = *(const s16x8*)(kp + ck * 32);
                    a = __builtin_amdgcn_mfma_f32_16x16x32_bf16(af[ck], bf, a, 0, 0, 0);
                }
                S[jt] = a;
            }
            __builtin_amdgcn_s_setprio(0);

            #pragma unroll
            for (int jt = 0; jt < 2; ++jt) {
                const int tbase = dlo8 + j0 + jt * 16 + l15 - 4 * g;
                #pragma unroll
                for (int r = 0; r < 4; ++r) {
                    const int wi = (tbase - r) & 255;
                    const unsigned sel = (wi & 0x80)
                        ? ((wi & 0x40) ? ((wi & 0x20) ? mk7 : mk6) : ((wi & 0x20) ? mk5 : mk4))
                        : ((wi & 0x40) ? ((wi & 0x20) ? mk3 : mk2) : ((wi & 0x20) ? mk1 : mk0));
                    if (!((sel >> (wi & 31)) & 1u)) S[jt][r] = -3e38f;
                }
            }

            float rmax[4];
            #pragma unroll
            for (int r = 0; r < 4; ++r) {
                float v = fmaxf(S[0][r], S[1][r]);
                v = fmaxf(v, __shfl_xor(v, 1));
                v = fmaxf(v, __shfl_xor(v, 2));
                v = fmaxf(v, __shfl_xor(v, 4));
                v = fmaxf(v, __shfl_xor(v, 8));
                rmax[r] = v;
            }
            int need = 0;
            #pragma unroll
            for (int r = 0; r < 4; ++r) need |= (rmax[r] > M[r] + 8.0f) ? 1 : 0;
            if (__any(need)) {
                #pragma unroll
                for (int r = 0; r < 4; ++r) {
                    const float Mn = fmaxf(M[r], rmax[r]);
                    const float f = __expf(M[r] - Mn);
                    M[r] = Mn; L[r] *= f;
                    #pragma unroll
                    for (int ct = 0; ct < 16; ++ct) O[ct][r] *= f;
                }
            }

            #pragma unroll
            for (int jt = 0; jt < 2; ++jt) {
                #pragma unroll
                for (int r = 0; r < 4; ++r) {
                    const float a = qw * __expf(S[jt][r] - M[r]);
                    const unsigned short ab = f2bf(a);
                    L[r] += bf2f(((unsigned)ab) << 16);
                    als[wv][4 * g + r][jt * 16 + l15] = ab;
                }
            }
            const s16x8 afr = *(const s16x8*)&als[wv][l15][g * 8];

            const int wj = (wbase + j0 + g * 8) & 255;
            __builtin_amdgcn_s_setprio(1);
            #pragma unroll
            for (int ct = 0; ct < 16; ++ct) {
                const s16x8 vb8 = *(const s16x8*)(vptr + (((size_t)(ct * 16 + l15)) << 8) + wj);
                O[ct] = __builtin_amdgcn_mfma_f32_16x16x32_bf16(afr, vb8, O[ct], 0, 0, 0);
            }
            __builtin_amdgcn_s_setprio(0);
        }
    }

    // ---- finalize: direct coalesced stores (lane holds 4 consecutive wo for one channel) ----
    float rL[4];
    #pragma unroll
    for (int r = 0; r < 4; ++r) {
        float v = L[r];
        v += __shfl_xor(v, 1);
        v += __shfl_xor(v, 2);
        v += __shfl_xor(v, 4);
        v += __shfl_xor(v, 8);
        rL[r] = 1.0f / v;
    }
    #pragma unroll
    for (int ct = 0; ct < 16; ++ct) {
        const int c = ct * 16 + l15;
        f32x4 o;
        o[0] = O[ct][0] * rL[0];
        o[1] = O[ct][1] * rL[1];
        o[2] = O[ct][2] * rL[2];
        o[3] = O[ct][3] * rL[3];
        *(f32x4*)(out + (((size_t)((b * NCH + c) * NLAT + ho)) << 8) + ws0 + 4 * g) = o;
    }
}

extern "C" void kernel_launch(void* const* d_in, const int* in_sizes, int n_in,
                              void* d_out, int out_size, void* d_ws, size_t ws_size,
                              hipStream_t stream) {
    const float* query = (const float*)d_in[0];
    const float* q_w   = (const float*)d_in[1];
    const float* k_w   = (const float*)d_in[2];
    const float* v_w   = (const float*)d_in[3];
    const float* q_b   = (const float*)d_in[4];
    const float* k_b   = (const float*)d_in[5];
    const float* v_b   = (const float*)d_in[6];
    const float* qwt   = (const float*)d_in[7];
    const int* psi_row = (const int*)d_in[8];
    const int* psi_col = (const int*)d_in[9];
    const int nnz      = in_sizes[8];

    char* ws = (char*)d_ws;
    unsigned short* qB  = (unsigned short*)(ws);
    unsigned short* kB  = (unsigned short*)(ws + 33554432);
    unsigned short* vT  = (unsigned short*)(ws + 67108864);
    unsigned short* Wbf = (unsigned short*)(ws + 100663296);
    int* rp             = (int*)(ws + 100663296 + 393216);
    unsigned short* qT  = (unsigned short*)d_out;   // 32MB scratch; overwritten by k_attn

    k_prep<<<dim3(4100), dim3(256), 0, stream>>>(query, q_w, k_w, v_w, psi_row, nnz, qT, Wbf, rp);
    k_qkv<<<dim3(512, 2, 3), dim3(256), 0, stream>>>(Wbf, qT, q_b, k_b, v_b, qB, kB, vT);
    k_attn<<<dim3(1024), dim3(256), 0, stream>>>(qB, kB, vT, psi_col, qwt, rp, (float*)d_out);
}